// Round 10
// baseline (290.721 us; speedup 1.0000x reference)
//
#include <hip/hip_runtime.h>
#include <hip/hip_bf16.h>

// Problem constants
#define Bb 8
#define Ss 8192
#define Dd 256             // DIN == DH == 256
#define Mm (Bb * Ss)       // 65536 rows
#define Nn 512             // 2*DH output cols of the GEMM
#define NCHUNK 128
#define CLEN (Ss / NCHUNK) // 64
#define TSP 64             // Ts row stride (u32); Ts overlays buf1 (16 KB)

typedef __hip_bfloat16 bf16;
typedef __attribute__((ext_vector_type(8))) short short8;
typedef __attribute__((ext_vector_type(4))) float f32x4;

// ---------------------------------------------------------------------------
// Pointwise: a = sigmoid(-gate), v = sigmoid(gate) * g(hidden)
// divide-free, clamp-free: exp overflow -> inf -> rcp -> 0 is the right limit.
// ---------------------------------------------------------------------------
__device__ __forceinline__ void av_from_gh(float gate, float hid, float& a,
                                           float& v) {
  const float eg = __expf(gate);
  a = __builtin_amdgcn_rcpf(1.f + eg);        // sigmoid(-gate) = 1 - z
  const float z = 1.f - a;                    // sigmoid(gate)
  const float eh = __expf(fminf(hid, 0.f));
  const float sig = eh * __builtin_amdgcn_rcpf(1.f + eh);
  const float gfun = (hid >= 0.f) ? (hid + 0.5f) : sig;
  v = z * gfun;
}

__device__ __forceinline__ unsigned pack_av(float a, float v) {
  union { bf16 h[2]; unsigned u; } o;
  o.h[0] = __float2bfloat16(a);
  o.h[1] = __float2bfloat16(v);
  return o.u;
}

__device__ __forceinline__ short8 cvt8(const float4& u0, const float4& u1) {
  const float vals[8] = {u0.x, u0.y, u0.z, u0.w, u1.x, u1.y, u1.z, u1.w};
  short8 r;
#pragma unroll
  for (int i = 0; i < 8; i++) {
    union { bf16 h; short s; } t;
    t.h = __float2bfloat16(vals[i]);
    r[i] = t.s;
  }
  return r;
}

// ---------------------------------------------------------------------------
// Fused GEMM + bias + pointwise + per-chunk scan summaries.
//
// v11 (= v7 hot paths, fixed-cost amortization):
//  * TILE-PAIR: each block processes 2 M-tiles (256 rows) in a 16-step
//    super-K-loop; grid halves to 1024 (1.33 dispatch rounds at 3 blk/CU
//    instead of 2.67), prologue paid once per 2 tiles, tile-1's first loads
//    issued during tile-0's steps 6-7 so tile-1 starts hot.
//  * LDS: buf0 = {A@0, B@8K}, buf1 = {A@16K, B@24K}. Every tile ends on an
//    odd step (bi==1) so buf1 is the free half during the epilogue -> Ts
//    (16 KB, TSP=64) overlays buf1; buf0 carries next tile's K0 across it.
//  * W consumed directly as f32, converted at ds_write (RNE, bit-identical
//    to a separate cvt pass) -> no cvt dispatch. DEPTH=2 (v10: depth-3 null).
//  * Everything else v7-proven: reg-staged one-barrier K-loop, XOR-swizzled
//    LDS, XCD-bijective swizzle (XCD x owns batch x), dense coalesced AV
//    stores via Ts, all-thread chunk summaries.
// ---------------------------------------------------------------------------
template <bool F32A>
__global__ __launch_bounds__(256, 3) void gemm_av_fused(
    const void* __restrict__ Xv, const float* __restrict__ Wf,
    const float* __restrict__ bias, unsigned* __restrict__ AV,
    float2* __restrict__ AVs) {
  __shared__ __align__(16) char sm[34816];
  bf16* Ab[2] = {(bf16*)sm, (bf16*)(sm + 16384)};
  bf16* Bbf[2] = {(bf16*)(sm + 8192), (bf16*)(sm + 24576)};
  unsigned* Ts = (unsigned*)(sm + 16384);  // epilogue overlay on buf1
  float2* Ps = (float2*)(sm + 32768);      // [4 seg][64 d]

  const int tid = threadIdx.x;
  const int w = tid >> 6;
  const int l = tid & 63;
  const int fl = l & 15;
  const int q = l >> 4;

  // XCD-bijective swizzle: xcd x owns lin [x*128,+128) = btp [x*32,+32)
  // = rows [x*8192,+8192) = batch x.
  const int id = blockIdx.x;
  const int lin = ((id & 7) << 7) | (id >> 3);  // bijective 0..1023
  const int cb = lin & 3;               // paired-channel block 0..3
  const int btp = lin >> 2;             // tile-pair 0..255
  const long rowBase0 = (long)btp * 256;
  const int wrow = (w >> 1) * 64;
  const int wc = (w & 1) * 32;

  const float* Xf = (const float*)Xv;
  const bf16* Xb = (const bf16*)Xv;

  // ---- staging addresses (hoisted): idx=c*256+tid -> row=idx>>2, kq=idx&3
  //      LDS layout [row][32 k], chunk swizzled: kq' = kq ^ ((row>>1)&3).
  const float* aSF[2];
  const bf16* aSB[2];
  const float* bSF[2];
  int ldsOff[2];
#pragma unroll
  for (int c = 0; c < 2; c++) {
    const int idx = c * 256 + tid;
    const int row = idx >> 2;
    const int kq = idx & 3;
    ldsOff[c] = row * 32 + (kq ^ ((row >> 1) & 3)) * 8;
    aSF[c] = Xf + (rowBase0 + row) * 256 + kq * 8;
    aSB[c] = Xb + (rowBase0 + row) * 256 + kq * 8;
    const int grow = (row < 64) ? (cb * 64 + row) : (192 + cb * 64 + row);
    bSF[c] = Wf + (long)grow * 256 + kq * 8;
  }

  // staging registers (one step in flight)
  short8 aReg[2];
  float4 aF[2][2];
  float4 bF[2][2];

  // step s = 0..15: tile = s>>3, K-step = s&7
  auto loadG = [&](int s) {
    const int so = (s >> 3) * (128 * 256) + (s & 7) * 32;
    if constexpr (F32A) {
#pragma unroll
      for (int c = 0; c < 2; c++) {
        aF[c][0] = *(const float4*)(aSF[c] + so);
        aF[c][1] = *(const float4*)(aSF[c] + so + 4);
      }
    } else {
#pragma unroll
      for (int c = 0; c < 2; c++)
        aReg[c] = *(const short8*)(aSB[c] + so);
    }
    const int sob = (s & 7) * 32;  // W identical across the 2 tiles
#pragma unroll
    for (int c = 0; c < 2; c++) {
      bF[c][0] = *(const float4*)(bSF[c] + sob);
      bF[c][1] = *(const float4*)(bSF[c] + sob + 4);
    }
  };
  auto writeL = [&](int bi) {
#pragma unroll
    for (int c = 0; c < 2; c++) {
      short8 av_;
      if constexpr (F32A)
        av_ = cvt8(aF[c][0], aF[c][1]);
      else
        av_ = aReg[c];
      *(short8*)(Ab[bi] + ldsOff[c]) = av_;
    }
#pragma unroll
    for (int c = 0; c < 2; c++)
      *(short8*)(Bbf[bi] + ldsOff[c]) = cvt8(bF[c][0], bF[c][1]);
  };

  // ---- fragment LDS offsets (hoisted, swizzle-matched, conflict-free)
  int aOff[4], bOff[4];
#pragma unroll
  for (int mt = 0; mt < 4; mt++) {
    const int row = wrow + 16 * mt + fl;
    aOff[mt] = row * 32 + (q ^ ((row >> 1) & 3)) * 8;
  }
#pragma unroll
  for (int nt = 0; nt < 4; nt++) {
    const int row =
        (nt < 2) ? (wc + 16 * nt + fl) : (64 + wc + 16 * (nt - 2) + fl);
    bOff[nt] = row * 32 + (q ^ ((row >> 1) & 3)) * 8;
  }

  // bias (hoisted)
  float bg[2], bh[2];
#pragma unroll
  for (int p = 0; p < 2; p++) {
    const int d = cb * 64 + wc + 16 * p + fl;
    bg[p] = bias[d];
    bh[p] = bias[256 + d];
  }

  f32x4 acc[4][4];
#pragma unroll
  for (int i = 0; i < 4; i++)
#pragma unroll
    for (int j = 0; j < 4; j++) acc[i][j] = (f32x4)0.0f;

  // ---- per-tile epilogue: pointwise + Ts transpose + dense AV + summaries
  auto epilogue = [&](int tt) {
    unsigned pk[4][2][4];
#pragma unroll
    for (int mt = 0; mt < 4; mt++)
#pragma unroll
      for (int p = 0; p < 2; p++)
#pragma unroll
        for (int r = 0; r < 4; r++) {
          float a, v;
          av_from_gh(acc[mt][p][r] + bg[p], acc[mt][p + 2][r] + bh[p], a, v);
          pk[mt][p][r] = pack_av(a, v);
        }
    const int bt = btp * 2 + tt;
    const long rowBase = rowBase0 + (long)tt * 128;
#pragma unroll
    for (int h = 0; h < 2; h++) {
      if ((w >> 1) == h) {
#pragma unroll
        for (int mt = 0; mt < 4; mt++)
#pragma unroll
          for (int p = 0; p < 2; p++)
#pragma unroll
            for (int r = 0; r < 4; r++)
              Ts[(16 * mt + 4 * q + r) * TSP + wc + 16 * p + fl] =
                  pk[mt][p][r];
      }
      __syncthreads();
      // dense AV half-tile: [64 rows][64 d] u32, 1KB/wave contiguous
      {
        unsigned* dst = AV + ((long)cb * Mm + rowBase + h * 64) * 64;
#pragma unroll
        for (int j = 0; j < 4; j++) {
          const int idx = j * 256 + tid;
          const int t = idx >> 4;
          const int d4 = idx & 15;
          const uint4 val = *(const uint4*)(Ts + t * TSP + d4 * 4);
          *(uint4*)(dst + 4 * idx) = val;
        }
      }
      // summary partials: thread (sg,dl) folds rows [sg*16,+16) of col dl
      {
        const int dl = tid & 63;
        const int sg = tid >> 6;
        float A = 1.f, H = 0.f;
#pragma unroll
        for (int t = 0; t < 16; t++) {
          const unsigned p = Ts[(sg * 16 + t) * TSP + dl];
          const float a = __uint_as_float((p & 0xffffu) << 16);
          const float v = __uint_as_float(p & 0xffff0000u);
          A *= a;
          H = a * H + v;
        }
        Ps[sg * 64 + dl] = make_float2(A, H);
      }
      __syncthreads();
      if (tid < 64) {
        float2 r = Ps[tid];  // segment 0
#pragma unroll
        for (int s = 1; s < 4; s++) {
          const float2 n = Ps[s * 64 + tid];
          r = make_float2(r.x * n.x, n.x * r.y + n.y);
        }
        const long cg = (long)(bt >> 6) * NCHUNK + ((bt & 63) << 1) + h;
        AVs[cg * 256 + cb * 64 + tid] = r;
      }
      __syncthreads();
    }
  };

  // ---- 16-step super-K-loop (2 tiles), reg-staged, one barrier per step.
  // Invariant at top of step s: buf[s&1] holds step s; regs hold step s+1.
  loadG(0);
  writeL(0);
  loadG(1);
  __syncthreads();
#pragma unroll
  for (int tile = 0; tile < 2; tile++) {
#pragma unroll
    for (int k = 0; k < 8; k++) {
      const int s = tile * 8 + k;
      const int bi = s & 1;
      short8 af[4], bf_[4];
#pragma unroll
      for (int mt = 0; mt < 4; mt++)
        af[mt] = *(const short8*)(Ab[bi] + aOff[mt]);
#pragma unroll
      for (int nt = 0; nt < 4; nt++)
        bf_[nt] = *(const short8*)(Bbf[bi] + bOff[nt]);
      if (s < 15) writeL(bi ^ 1);   // step s+1 -> other buffer
      if (s < 14) loadG(s + 2);     // issue step s+2 global loads
#pragma unroll
      for (int mt = 0; mt < 4; mt++)
#pragma unroll
        for (int nt = 0; nt < 4; nt++)
          acc[mt][nt] = __builtin_amdgcn_mfma_f32_16x16x32_bf16(
              af[mt], bf_[nt], acc[mt][nt], 0, 0, 0);
      asm volatile("s_waitcnt lgkmcnt(0)" ::: "memory");
      __builtin_amdgcn_s_barrier();
    }
    // tile ends on odd step (bi==1): buf1 free -> Ts overlay; buf0 holds
    // next tile's K0 (written at s==7); regs hold its K1 (issued at s==7).
    epilogue(tile);
    if (tile == 0) {
#pragma unroll
      for (int i = 0; i < 4; i++)
#pragma unroll
        for (int j = 0; j < 4; j++) acc[i][j] = (f32x4)0.0f;
    }
  }
}

// ---------------------------------------------------------------------------
// Final scan. Prologue folds this chunk's prefix from the (L3-hot, 2MB)
// chunk-summary table (independent loads). WRITE_BF16 ? bf16 : f32 stream.
// AV layout: [cb 4][row][64 d] u32 (matches gemm's dense writes).
// ---------------------------------------------------------------------------
template <bool WRITE_BF16>
__global__ __launch_bounds__(256) void scan_final(
    const unsigned* __restrict__ AV, const float2* __restrict__ AVs,
    bf16* __restrict__ OutB, float* __restrict__ OutF,
    float* __restrict__ Hlast) {
  const int d = threadIdx.x;
  const int c = blockIdx.x % NCHUNK;
  const int b = blockIdx.x / NCHUNK;

  float h = 0.5f;  // h0 = g(0) = 0.5
#pragma unroll 4
  for (int j = 0; j < c; j++) {
    const float2 av = AVs[((long)b * NCHUNK + j) * 256 + d];
    h = av.x * h + av.y;
  }

  const long row0 = (long)b * Ss + (long)c * CLEN;
  const unsigned* src = AV + (long)(d >> 6) * Mm * 64 + (d & 63);
  long obase = row0 * 256 + d;
#pragma unroll 8
  for (int t = 0; t < CLEN; t++) {
    const unsigned p = src[(row0 + t) * 64];
    const float a = __uint_as_float((p & 0xffffu) << 16);
    const float v = __uint_as_float(p & 0xffff0000u);
    h = a * h + v;
    if (WRITE_BF16)
      OutB[obase] = __float2bfloat16(h);
    else
      OutF[obase] = h;
    obase += 256;
  }
  if (c == NCHUNK - 1) Hlast[b * 256 + d] = h;
}

// ---------------------------------------------------------------------------
extern "C" void kernel_launch(void* const* d_in, const int* in_sizes, int n_in,
                              void* d_out, int out_size, void* d_ws,
                              size_t ws_size, hipStream_t stream) {
  const float* x = (const float*)d_in[0];
  const float* W0f = (const float*)d_in[1];
  const float* b0 = (const float*)d_in[2];
  const float* W1f = (const float*)d_in[3];
  const float* b1 = (const float*)d_in[4];

  float* outF = (float*)d_out;              // out1 (f32), Mm*256 elements
  float* hlast = outF + (long)Mm * 256;     // h: (2,8,1,256) f32
  // d_out's first 32 MiB doubles as bf16 scratch for X1 (dead before the
  // final f32 out-write overwrites it; ordering is stream-sequential).
  bf16* X1b = (bf16*)d_out;

  char* ws = (char*)d_ws;
  unsigned* AV = (unsigned*)ws;                      // 4*Mm*64 u32 = 64 MiB
  float2* AVs = (float2*)(ws + (long)Mm * 256 * 4);  // [Bb*NCHUNK][256] = 2 MiB

  const dim3 gemmGrid(1024);  // tile-pairs; XCD-bijective swizzle in-kernel
  const dim3 blk(256);

  // Layer 0 (A = f32 x; W = f32, converted at stage time)
  gemm_av_fused<true><<<gemmGrid, blk, 0, stream>>>(x, W0f, b0, AV, AVs);
  scan_final<true><<<dim3(Bb * NCHUNK), blk, 0, stream>>>(AV, AVs, X1b,
                                                          nullptr, hlast);

  // Layer 1 (A = bf16 X1 in d_out scratch; W = f32)
  gemm_av_fused<false><<<gemmGrid, blk, 0, stream>>>(X1b, W1f, b1, AV, AVs);
  scan_final<false><<<dim3(Bb * NCHUNK), blk, 0, stream>>>(
      AV, AVs, nullptr, outF, hlast + Bb * 256);
}

// Round 11
// 240.062 us; speedup vs baseline: 1.2110x; 1.2110x over previous
//
#include <hip/hip_runtime.h>
#include <hip/hip_bf16.h>

// Problem constants
#define Bb 8
#define Ss 8192
#define Dd 256             // DIN == DH == 256
#define Mm (Bb * Ss)       // 65536 rows
#define Nn 512             // 2*DH output cols of the GEMM
#define NCHUNK 128
#define CLEN (Ss / NCHUNK) // 64
#define TSP 68             // Ts row stride (u32): 64 + 4 pad

typedef __hip_bfloat16 bf16;
typedef __attribute__((ext_vector_type(8))) short short8;
typedef __attribute__((ext_vector_type(4))) float f32x4;

// ---------------------------------------------------------------------------
// f32 -> bf16 convert, both weight matrices in one launch
// ---------------------------------------------------------------------------
__global__ __launch_bounds__(256) void cvt_weights(
    const float* __restrict__ inA, const float* __restrict__ inB,
    bf16* __restrict__ outA, bf16* __restrict__ outB, long n4each) {
  long i = (long)blockIdx.x * blockDim.x + threadIdx.x;
  const float* in = inA;
  bf16* out = outA;
  if (i >= n4each) {
    in = inB;
    out = outB;
    i -= n4each;
  }
  if (i >= n4each) return;
  const float4 v = ((const float4*)in)[i];
  union { ushort4 u; bf16 h[4]; } o;
  o.h[0] = __float2bfloat16(v.x);
  o.h[1] = __float2bfloat16(v.y);
  o.h[2] = __float2bfloat16(v.z);
  o.h[3] = __float2bfloat16(v.w);
  ((ushort4*)out)[i] = o.u;
}

// ---------------------------------------------------------------------------
// Pointwise: a = sigmoid(-gate), v = sigmoid(gate) * g(hidden)
// divide-free, clamp-free: exp overflow -> inf -> rcp -> 0 is the right limit.
// ---------------------------------------------------------------------------
__device__ __forceinline__ void av_from_gh(float gate, float hid, float& a,
                                           float& v) {
  const float eg = __expf(gate);
  a = __builtin_amdgcn_rcpf(1.f + eg);        // sigmoid(-gate) = 1 - z
  const float z = 1.f - a;                    // sigmoid(gate)
  const float eh = __expf(fminf(hid, 0.f));
  const float sig = eh * __builtin_amdgcn_rcpf(1.f + eh);
  const float gfun = (hid >= 0.f) ? (hid + 0.5f) : sig;
  v = z * gfun;
}

__device__ __forceinline__ unsigned pack_av(float a, float v) {
  union { bf16 h[2]; unsigned u; } o;
  o.h[0] = __float2bfloat16(a);
  o.h[1] = __float2bfloat16(v);
  return o.u;
}

// ---------------------------------------------------------------------------
// Fused GEMM + bias + pointwise + per-chunk scan summaries.
// v12 = v7 VERBATIM (the 242us champion): reg-staged global->VGPR->ds_write
// staging, one barrier per K-step, 2-step lookahead, XOR-swizzled LDS,
// XCD-bijective block swizzle, dense coalesced AV stores via Ts transpose,
// all-thread chunk summaries.
// ---------------------------------------------------------------------------
template <bool F32A>
__global__ __launch_bounds__(256, 3) void gemm_av_fused(
    const void* __restrict__ Xv, const bf16* __restrict__ W,
    const float* __restrict__ bias, unsigned* __restrict__ AV,
    float2* __restrict__ AVs) {
  __shared__ __align__(16) char sm[32768];
  bf16* Ab[2] = {(bf16*)sm, (bf16*)(sm + 8192)};
  bf16* Bbf[2] = {(bf16*)(sm + 16384), (bf16*)(sm + 24576)};
  unsigned* Ts = (unsigned*)sm;            // post-K overlay: [64 t][TSP] u32
  float2* Ps = (float2*)(sm + 20480);      // summary partials: [4 seg][64 d]

  const int tid = threadIdx.x;
  const int w = tid >> 6;
  const int l = tid & 63;
  const int fl = l & 15;
  const int q = l >> 4;

  // XCD-bijective swizzle: xcd owns lin [xcd*256,+256) = bt in [xcd*64,+64)
  const int id = blockIdx.x;
  const int lin = ((id & 7) << 8) | (id >> 3);
  const int cb = lin & 3;              // paired-channel block 0..3
  const int bt = lin >> 2;             // M-tile 0..511
  const long rowBase = (long)bt * 128;
  const int wrow = (w >> 1) * 64;
  const int wc = (w & 1) * 32;

  const float* Xf = (const float*)Xv;
  const bf16* Xb = (const bf16*)Xv;

  // ---- staging addresses (hoisted). Thread covers 2 (row,kq) slots:
  //      idx = c*256+tid -> row = idx>>2 (0..127), kq = idx&3 (8-bf16 chunk).
  //      LDS layout [row][32 k], chunk swizzled: kq' = kq ^ ((row>>1)&3).
  const float* aSF[2];
  const bf16* aSB[2];
  const bf16* bS[2];
  int ldsOff[2];
#pragma unroll
  for (int c = 0; c < 2; c++) {
    const int idx = c * 256 + tid;
    const int row = idx >> 2;
    const int kq = idx & 3;
    ldsOff[c] = row * 32 + (kq ^ ((row >> 1) & 3)) * 8;
    aSF[c] = Xf + (rowBase + row) * 256 + kq * 8;
    aSB[c] = Xb + (rowBase + row) * 256 + kq * 8;
    const int grow = (row < 64) ? (cb * 64 + row) : (192 + cb * 64 + row);
    bS[c] = W + (long)grow * 256 + kq * 8;
  }

  // staging registers (tile in flight)
  short8 aReg[2], bReg[2];
  float4 aF[2][2];

  auto loadG = [&](int ks) {
    if constexpr (F32A) {
#pragma unroll
      for (int c = 0; c < 2; c++) {
        aF[c][0] = *(const float4*)(aSF[c] + ks * 32);
        aF[c][1] = *(const float4*)(aSF[c] + ks * 32 + 4);
      }
    } else {
#pragma unroll
      for (int c = 0; c < 2; c++)
        aReg[c] = *(const short8*)(aSB[c] + ks * 32);
    }
#pragma unroll
    for (int c = 0; c < 2; c++)
      bReg[c] = *(const short8*)(bS[c] + ks * 32);
  };
  auto writeL = [&](int bi) {
#pragma unroll
    for (int c = 0; c < 2; c++) {
      short8 av_;
      if constexpr (F32A) {
        const float vals[8] = {aF[c][0].x, aF[c][0].y, aF[c][0].z, aF[c][0].w,
                               aF[c][1].x, aF[c][1].y, aF[c][1].z, aF[c][1].w};
#pragma unroll
        for (int i = 0; i < 8; i++) {
          union { bf16 h; short s; } t;
          t.h = __float2bfloat16(vals[i]);
          av_[i] = t.s;
        }
      } else {
        av_ = aReg[c];
      }
      *(short8*)(Ab[bi] + ldsOff[c]) = av_;
    }
#pragma unroll
    for (int c = 0; c < 2; c++)
      *(short8*)(Bbf[bi] + ldsOff[c]) = bReg[c];
  };

  // ---- fragment LDS offsets (hoisted, swizzle-matched, conflict-free)
  int aOff[4], bOff[4];
#pragma unroll
  for (int mt = 0; mt < 4; mt++) {
    const int row = wrow + 16 * mt + fl;
    aOff[mt] = row * 32 + (q ^ ((row >> 1) & 3)) * 8;
  }
#pragma unroll
  for (int nt = 0; nt < 4; nt++) {
    const int row =
        (nt < 2) ? (wc + 16 * nt + fl) : (64 + wc + 16 * (nt - 2) + fl);
    bOff[nt] = row * 32 + (q ^ ((row >> 1) & 3)) * 8;
  }

  f32x4 acc[4][4];
#pragma unroll
  for (int i = 0; i < 4; i++)
#pragma unroll
    for (int j = 0; j < 4; j++) acc[i][j] = (f32x4)0.0f;

  // ---- K-loop: reg-staged, ONE barrier per step (v6/v7, best-known).
  loadG(0);
  writeL(0);
  loadG(1);
  __syncthreads();
#pragma unroll
  for (int ks = 0; ks < 8; ks++) {
    const int bi = ks & 1;
    short8 af[4], bf_[4];
#pragma unroll
    for (int mt = 0; mt < 4; mt++)
      af[mt] = *(const short8*)(Ab[bi] + aOff[mt]);
#pragma unroll
    for (int nt = 0; nt < 4; nt++)
      bf_[nt] = *(const short8*)(Bbf[bi] + bOff[nt]);
    if (ks < 7) writeL(bi ^ 1);   // tile ks+1 -> other buffer
    if (ks < 6) loadG(ks + 2);    // issue next-next tile's global loads
#pragma unroll
    for (int mt = 0; mt < 4; mt++)
#pragma unroll
      for (int nt = 0; nt < 4; nt++)
        acc[mt][nt] = __builtin_amdgcn_mfma_f32_16x16x32_bf16(
            af[mt], bf_[nt], acc[mt][nt], 0, 0, 0);
    asm volatile("s_waitcnt lgkmcnt(0)" ::: "memory");
    __builtin_amdgcn_s_barrier();
  }

  // ---- Epilogue: bias + pointwise + pack (registers only)
  float bg[2], bh[2];
#pragma unroll
  for (int p = 0; p < 2; p++) {
    const int d = cb * 64 + wc + 16 * p + fl;
    bg[p] = bias[d];
    bh[p] = bias[256 + d];
  }
  unsigned pk[4][2][4];
#pragma unroll
  for (int mt = 0; mt < 4; mt++)
#pragma unroll
    for (int p = 0; p < 2; p++)
#pragma unroll
      for (int r = 0; r < 4; r++) {
        float a, v;
        av_from_gh(acc[mt][p][r] + bg[p], acc[mt][p + 2][r] + bh[p], a, v);
        pk[mt][p][r] = pack_av(a, v);
      }

  // ---- Two 64-row halves through LDS transpose:
  //      dense coalesced AV stores + all-thread per-chunk scan summaries
#pragma unroll
  for (int h = 0; h < 2; h++) {
    if ((w >> 1) == h) {
#pragma unroll
      for (int mt = 0; mt < 4; mt++)
#pragma unroll
        for (int p = 0; p < 2; p++)
#pragma unroll
          for (int r = 0; r < 4; r++)
            Ts[(16 * mt + 4 * q + r) * TSP + wc + 16 * p + fl] = pk[mt][p][r];
    }
    __syncthreads();
    // dense AV half-tile: [64 rows][64 d] u32 -> 1KB/wave contiguous stores
    {
      unsigned* dst = AV + ((long)cb * Mm + rowBase + h * 64) * 64;
#pragma unroll
      for (int j = 0; j < 4; j++) {
        const int idx = j * 256 + tid;
        const int t = idx >> 4;
        const int d4 = idx & 15;
        const uint4 val = *(const uint4*)(Ts + t * TSP + d4 * 4);
        *(uint4*)(dst + 4 * idx) = val;
      }
    }
    // summary partials: thread (sg, dl) folds rows [sg*16, +16) of column dl
    {
      const int dl = tid & 63;
      const int sg = tid >> 6;
      float A = 1.f, H = 0.f;
#pragma unroll
      for (int t = 0; t < 16; t++) {
        const unsigned p = Ts[(sg * 16 + t) * TSP + dl];
        const float a = __uint_as_float((p & 0xffffu) << 16);
        const float v = __uint_as_float(p & 0xffff0000u);
        A *= a;
        H = a * H + v;
      }
      Ps[sg * 64 + dl] = make_float2(A, H);
    }
    __syncthreads();
    if (tid < 64) {
      float2 r = Ps[tid];  // segment 0
#pragma unroll
      for (int s = 1; s < 4; s++) {
        const float2 n = Ps[s * 64 + tid];
        r = make_float2(r.x * n.x, n.x * r.y + n.y);  // apply seg s after r
      }
      const long cg = (long)(bt >> 6) * NCHUNK + ((bt & 63) << 1) + h;
      AVs[cg * 256 + cb * 64 + tid] = r;
    }
    __syncthreads();
  }
}

// ---------------------------------------------------------------------------
// Final scan, v12: 2 chunks per block (512 blocks) -- prefix folded once per
// pair, h carried across the chunk boundary; unroll 16 (deeper MLP on the
// latency-bound AV walk); XCD-bijective swizzle so batch b is processed on
// XCD b (matching the gemm's AV-writer placement -> L2/L3-local reads).
// AV layout: [cb 4][row][64 d] u32 (matches gemm's dense writes).
// ---------------------------------------------------------------------------
template <bool WRITE_BF16>
__global__ __launch_bounds__(256) void scan_final(
    const unsigned* __restrict__ AV, const float2* __restrict__ AVs,
    bf16* __restrict__ OutB, float* __restrict__ OutF,
    float* __restrict__ Hlast) {
  const int d = threadIdx.x;
  const int id = blockIdx.x;     // 512 blocks
  const int b = id & 7;          // batch = XCD that wrote this AV panel
  const int cpair = id >> 3;     // 0..63 -> chunks 2*cpair, 2*cpair+1
  const int c0 = cpair * 2;

  float h = 0.5f;  // h0 = g(0) = 0.5
#pragma unroll 4
  for (int j = 0; j < c0; j++) {
    const float2 av = AVs[((long)b * NCHUNK + j) * 256 + d];
    h = av.x * h + av.y;
  }

  const long row0 = (long)b * Ss + (long)c0 * CLEN;
  const unsigned* src = AV + (long)(d >> 6) * Mm * 64 + (d & 63);
  long obase = row0 * 256 + d;
#pragma unroll 16
  for (int t = 0; t < 2 * CLEN; t++) {
    const unsigned p = src[(row0 + t) * 64];
    const float a = __uint_as_float((p & 0xffffu) << 16);
    const float v = __uint_as_float(p & 0xffff0000u);
    h = a * h + v;
    if (WRITE_BF16)
      OutB[obase] = __float2bfloat16(h);
    else
      OutF[obase] = h;
    obase += 256;
  }
  if (cpair == NCHUNK / 2 - 1) Hlast[b * 256 + d] = h;
}

// ---------------------------------------------------------------------------
extern "C" void kernel_launch(void* const* d_in, const int* in_sizes, int n_in,
                              void* d_out, int out_size, void* d_ws,
                              size_t ws_size, hipStream_t stream) {
  const float* x = (const float*)d_in[0];
  const float* W0f = (const float*)d_in[1];
  const float* b0 = (const float*)d_in[2];
  const float* W1f = (const float*)d_in[3];
  const float* b1 = (const float*)d_in[4];

  float* outF = (float*)d_out;              // out1 (f32), Mm*256 elements
  float* hlast = outF + (long)Mm * 256;     // h: (2,8,1,256) f32
  // d_out's first 32 MiB doubles as bf16 scratch for X1 (dead before the
  // final f32 out-write overwrites it; ordering is stream-sequential).
  bf16* X1b = (bf16*)d_out;

  char* ws = (char*)d_ws;
  unsigned* AV = (unsigned*)ws;                      // 4*Mm*64 u32 = 64 MiB
  bf16* W0b = (bf16*)(ws + (long)Mm * 256 * 4);      // 512*256 bf16
  bf16* W1b = W0b + (long)Nn * Dd;
  float2* AVs = (float2*)(W1b + (long)Nn * Dd);      // [Bb*NCHUNK][256] = 2 MiB

  const dim3 gemmGrid(2048);  // 1-D, XCD-bijective swizzle decoded in-kernel
  const dim3 blk(256);
  const dim3 scanGrid(Bb * NCHUNK / 2);  // 512: 2 chunks per block

  // Convert both weight matrices to bf16 in one launch
  const long n4w = (long)Nn * Dd / 4;
  cvt_weights<<<dim3((2 * n4w + 255) / 256), blk, 0, stream>>>(W0f, W1f, W0b,
                                                               W1b, n4w);

  // Layer 0 (A = f32 x, reg-staged, converted once at stage time)
  gemm_av_fused<true><<<gemmGrid, blk, 0, stream>>>(x, W0b, b0, AV, AVs);
  scan_final<true><<<scanGrid, blk, 0, stream>>>(AV, AVs, X1b, nullptr,
                                                 hlast);

  // Layer 1 (A = bf16 X1 in d_out scratch)
  gemm_av_fused<false><<<gemmGrid, blk, 0, stream>>>(X1b, W1b, b1, AV, AVs);
  scan_final<false><<<scanGrid, blk, 0, stream>>>(AV, AVs, nullptr, outF,
                                                  hlast + Bb * 256);
}